// Round 10
// baseline (334.413 us; speedup 1.0000x reference)
//
#include <hip/hip_runtime.h>
#include <hip/hip_bf16.h>

#define NDIM 128
#define MROWS 32           // rows per block (two 16-row MFMA tiles)
#define BTHREADS 512       // 8 waves per block
#define SCAN_CHUNK 1024    // per block: 256 threads x 4 elements

typedef __attribute__((ext_vector_type(8))) short short8;
typedef __attribute__((ext_vector_type(4))) float f32x4;
typedef unsigned uint4v __attribute__((ext_vector_type(4)));

__device__ __forceinline__ float bf2f(__hip_bfloat16 v) { return __bfloat162float(v); }

__device__ __forceinline__ float ldf(const void* p, long i, int f32) {
    return f32 ? ((const float*)p)[i] : bf2f(((const __hip_bfloat16*)p)[i]);
}
__device__ __forceinline__ void stf(void* p, long i, int f32, float v) {
    if (f32) ((float*)p)[i] = v;
    else     ((__hip_bfloat16*)p)[i] = __float2bfloat16(v);
}
__device__ __forceinline__ short f2bf(float v) {
    __hip_bfloat16 h = __float2bfloat16(v);
    short s;
    __builtin_memcpy(&s, &h, 2);
    return s;
}
// bf16x2 packed in a uint: low halfword = even feature, high = odd feature
__device__ __forceinline__ float bflo(unsigned u) { u <<= 16; float f; __builtin_memcpy(&f, &u, 4); return f; }
__device__ __forceinline__ float bfhi(unsigned u) { u &= 0xffff0000u; float f; __builtin_memcpy(&f, &u, 4); return f; }
__device__ __forceinline__ unsigned packbf(float a, float b) {
    unsigned la = (unsigned short)f2bf(a);
    unsigned hb = (unsigned short)f2bf(b);
    return (hb << 16) | la;
}
// Swizzled LDS index (shorts) for A-tiles: 16B-chunk XOR by (row&7).
__device__ __forceinline__ int aswz(int m, int k) {
    return m * NDIM + ((((k >> 3) ^ (m & 7)) << 3) | (k & 7));
}

// asm-pinned 16B gather loads: result VGPRs stay allocated, loads cannot be
// sunk into consumers (R5-R8 showed source-level pipelines collapse).
// CRITICAL (R9 lesson): no compiler-tracked memory op may sit between these
// and the explicit s_waitcnt — the compiler would emit its own vmcnt(0).
#define GLOAD4V(dst, va)                                                  \
    asm volatile("global_load_dwordx4 %0, %1, off"                        \
                 : "=v"(dst) : "v"(va) : "memory")
#define GLOAD4S(dst, sa, voff)                                            \
    asm volatile("global_load_dwordx4 %0, %1, %2"                         \
                 : "=v"(dst) : "v"(voff), "s"(sa) : "memory")

// ---- prep: per-block dtype detection + weights + biases + degree pass ------

__global__ void prep_kernel(const void* __restrict__ x,
                            const void* __restrict__ W1l, const void* __restrict__ b1l,
                            const void* __restrict__ W1r, const void* __restrict__ W2l,
                            const void* __restrict__ b2l, const void* __restrict__ W2r,
                            const void* __restrict__ Wd,
                            short* __restrict__ T1l, short* __restrict__ T1r,
                            short* __restrict__ T2l, short* __restrict__ T2r,
                            short* __restrict__ Td, float* __restrict__ b1c,
                            float* __restrict__ b2c, unsigned* __restrict__ xb,
                            const int* __restrict__ xedge, int E,
                            int* __restrict__ cnt, int N,
                            int* __restrict__ flags) {
    __shared__ int s_se, s_sc;
    const int t = threadIdx.x;
    if (t == 0) { s_se = 1; s_sc = 0; }
    __syncthreads();
    {
        for (int i = t; i < 512; i += 256)
            if (xedge[2 * i + 1] != 0) s_se = 0;
        const unsigned short* xh = (const unsigned short*)x;
        int c = 0;
        for (int i = t; i < 1024; i += 256) {
            int ex = (xh[2 * i] >> 7) & 0xFF;
            if (ex >= 100 && ex <= 150) c++;
        }
        atomicAdd(&s_sc, c);
    }
    __syncthreads();
    const int e64 = s_se;
    const int wf = (s_sc < 900) ? 1 : 0;
    if (blockIdx.x == 0 && t == 0) {
        flags[0] = e64;
        flags[2] = wf;
    }
    const long idx = (long)blockIdx.x * 256 + t;
    if (idx < E) {
        int d = e64 ? xedge[2 * (E + idx)] : xedge[E + idx];
        atomicAdd(&cnt[d], 1);
    }
    if (idx < NDIM * NDIM) {
        int k = (int)(idx >> 7), n = (int)(idx & 127);
        int o = n * NDIM + k;
        T1l[o] = f2bf(ldf(W1l, idx, wf));
        T1r[o] = f2bf(ldf(W1r, idx, wf));
        T2l[o] = f2bf(ldf(W2l, idx, wf));
        T2r[o] = f2bf(ldf(W2r, idx, wf));
        Td [o] = f2bf(ldf(Wd , idx, wf));
        if (idx < NDIM) { b1c[idx] = ldf(b1l, idx, wf); b2c[idx] = ldf(b2l, idx, wf); }
    }
    if (wf) {
        const long np = (long)N * 64;
        const long stride = (long)gridDim.x * 256;
        for (long pidx = idx; pidx < np; pidx += stride) {
            float2 v = ((const float2*)x)[pidx];
            xb[pidx] = packbf(v.x, v.y);
        }
    }
}

// ---- 2-kernel exclusive scan: partial sums, then scatter with self-prefix --
// (scan_bsums eliminated: each scatter block sums bsum[0..blockIdx) itself —
// <=49 ints, L2-broadcast. y-dtype probe folded into scan_partial block 0.)

__global__ void scan_partial(const int* __restrict__ cnt, int* __restrict__ bsum, int N,
                             const unsigned int* __restrict__ yw,
                             int* __restrict__ flags) {
    __shared__ int red[256];
    const int t = threadIdx.x;
    if (blockIdx.x == 0) {
        __shared__ int s_sy;
        if (t == 0) s_sy = 0;
        __syncthreads();
        for (int i = t; i < 1024; i += 256)
            if (yw[i] > 1u) s_sy = 1;
        __syncthreads();
        if (t == 0) flags[1] = s_sy;
    }
    const long base = (long)blockIdx.x * SCAN_CHUNK + (long)t * 4;
    int s = 0;
#pragma unroll
    for (int i = 0; i < 4; ++i) { long idx = base + i; if (idx < N) s += cnt[idx]; }
    red[t] = s;
    __syncthreads();
    for (int off = 128; off >= 1; off >>= 1) {
        if (t < off) red[t] += red[t + off];
        __syncthreads();
    }
    if (t == 0) bsum[blockIdx.x] = red[0];
}

__global__ void scan_scatter(int* __restrict__ cnt, const int* __restrict__ bsum,
                             int* __restrict__ rowptr, int N) {
    __shared__ int tsum[256];
    __shared__ int red[256];
    const int t = threadIdx.x;
    const long base = (long)blockIdx.x * SCAN_CHUNK + (long)t * 4;
    int loc[4];
    int s = 0;
#pragma unroll
    for (int i = 0; i < 4; ++i) {
        long idx = base + i;
        int c = (idx < N) ? cnt[idx] : 0;
        loc[i] = s;
        s += c;
    }
    tsum[t] = s;
    // self-prefix over previous blocks' sums
    int sown = 0;
    for (int i = t; i < blockIdx.x; i += 256) sown += bsum[i];
    red[t] = sown;
    __syncthreads();
    for (int off = 1; off < 256; off <<= 1) {
        int u = (t >= off) ? tsum[t - off] : 0;
        __syncthreads();
        tsum[t] += u;
        __syncthreads();
    }
    for (int off = 128; off >= 1; off >>= 1) {
        if (t < off) red[t] += red[t + off];
        __syncthreads();
    }
    const int b0 = red[0];
    const int texcl = tsum[t] - s;
#pragma unroll
    for (int i = 0; i < 4; ++i) {
        long idx = base + i;
        if (idx < N) {
            int v = b0 + texcl + loc[i];
            rowptr[idx] = v;
            cnt[idx] = v;   // cursor seed for fill
        }
    }
    if (blockIdx.x == gridDim.x - 1 && t == 255) rowptr[N] = b0 + tsum[255];
}

__global__ void fill_kernel(const int* __restrict__ xedge, int E,
                            const int* __restrict__ flags,
                            int* __restrict__ cur, int* __restrict__ col) {
    int e = blockIdx.x * blockDim.x + threadIdx.x;
    if (e >= E) return;
    const int e64 = flags[0];
    int s = e64 ? xedge[2 * e] : xedge[e];
    int d = e64 ? xedge[2 * (E + e)] : xedge[E + e];
    int p = atomicAdd(&cur[d], 1);
    col[p] = s;
}

// ---- SAGE layer: 32-row blocks, 8 waves, 4 rows/wave. Wide gather:
// 16 lanes x dwordx4 per row (1KB/instruction): lane l covers features
// [8*(l&15), +8) of edge subset {j : j mod 4 == l>>4}. Per row: 1 coalesced
// col vector load -> shfl-distribute -> 8 asm-pinned global_load_dwordx4 +
// self row -> ONE vmcnt(0) -> masked subset sums -> 2 shfl_xor rounds ->
// rare deg>32 tail -> mean -> 16B swizzled LDS write (lanes 0-15).
// ORDERING INVARIANT (R9 lesson): all compiler-tracked loads (colv, rowptr
// prefetch) issue AND are consumed before any asm load, so the compiler
// never inserts its own vmcnt wait inside the pinned window.
// OUTMODE 0: bf16 out (outp=hbuf). OUTMODE 1: fused emb store + decoder
// MFMA + BCE loss. Xb = converted bf16x2 (wf==1); Xraw = raw bf16 (wf==0).

template <bool RELU, int OUTMODE>
__global__ __launch_bounds__(BTHREADS, 2)
void layer_mfma(const unsigned* __restrict__ Xb, const unsigned* __restrict__ Xraw,
                const int* __restrict__ rowptr,
                const int* __restrict__ col, const short* __restrict__ WlT,
                const float* __restrict__ biasc, const short* __restrict__ WrT,
                const short* __restrict__ WdT, const void* __restrict__ yv,
                const int* __restrict__ flags, void* __restrict__ outp,
                float* __restrict__ accum, int* __restrict__ npos, int N) {
    __shared__ short AS[2 * MROWS * NDIM];  // [Ms 8KB][Ss 8KB]
    __shared__ int ylds[MROWS];
    __shared__ float redm[8][2];
    short* Ms = AS;
    short* Ss = AS + MROWS * NDIM;
    unsigned* Msw = (unsigned*)Ms;
    uint4v* Msw4 = (uint4v*)Ms;
    uint4v* Ssw4 = (uint4v*)Ss;
    const int t = threadIdx.x;
    const int n0 = blockIdx.x * MROWS;
    const int wf = flags[2];
    const unsigned* __restrict__ X = wf ? Xb : Xraw;

    if (OUTMODE == 1 && t < MROWS) {
        const int yb = flags[1];
        int n = n0 + t;
        int yn = -1;
        if (n < N)
            yn = yb ? (int)((const unsigned char*)yv)[n]
                    : (((const int*)yv)[n] != 0 ? 1 : 0);
        ylds[t] = yn;
    }

    // ---- gather: 8 row-groups (one wave each), 4 rows/wave ------------------
    {
        const int l = t & 63;
        const int g16 = l >> 4;     // edge-subset group 0..3
        const int q = l & 15;       // feature-quad (uint4 index within row)
        const unsigned long long Xb64 = (unsigned long long)(uintptr_t)X;
        const unsigned long long base16 = Xb64 + (unsigned)(q << 4);
        const unsigned voff16 = (unsigned)(q << 4);
        const int wv = __builtin_amdgcn_readfirstlane(t >> 6);
        int r = wv;
        int b = 0, e = 0;
        {
            int n = n0 + r;
            if (n < N) {
                b = __builtin_amdgcn_readfirstlane(rowptr[n]);
                e = __builtin_amdgcn_readfirstlane(rowptr[n + 1]);
            }
        }
        for (int it = 0; it < 4; ++it, r += 8) {
            const int n = n0 + r;
            const int deg = e - b;
            // --- compiler-tracked loads FIRST (colv + rowptr prefetch) ---
            int colv = 0;
            if (deg > 0) {
                int cl = b + (l & 31);
                if (cl >= e) cl = e - 1;
                colv = col[cl];
            }
            int bn = 0, en = 0;
            if (it < 3) {
                int nn = n0 + r + 8;
                if (nn < N) {
                    bn = __builtin_amdgcn_readfirstlane(rowptr[nn]);
                    en = __builtin_amdgcn_readfirstlane(rowptr[nn + 1]);
                }
            }
            // distribute col values (consumes colv — compiler wait lands here)
            int c[8];
            if (deg > 0) {
#pragma unroll
                for (int i = 0; i < 8; ++i) {
                    int ci = __shfl(colv, 4 * i + g16, 64);
                    c[i] = ((unsigned)ci >= (unsigned)N) ? 0 : ci;
                }
            }
            // --- asm-pinned loads: nothing compiler-tracked below until wait ---
            uint4v u4[8];
            uint4v su4 = {0, 0, 0, 0};
            const int havesu = (n < N) && (l < 16);
            if (havesu) {
                unsigned long long sa = Xb64 + ((unsigned long long)(unsigned)n << 8);
                GLOAD4S(su4, sa, voff16);
            }
            if (deg > 0) {
#pragma unroll
                for (int i = 0; i < 8; ++i) {
                    unsigned long long va = base16 + ((unsigned long long)(unsigned)c[i] << 8);
                    GLOAD4V(u4[i], va);
                }
            }
            asm volatile("s_waitcnt vmcnt(0)" ::: "memory");
            __builtin_amdgcn_sched_barrier(0);
            if (havesu) asm volatile("" : "+v"(su4));
            if (deg > 0) {
#pragma unroll
                for (int i = 0; i < 8; ++i) asm volatile("" : "+v"(u4[i]));
            }
            // --- masked subset sums (exact: only real edges, each once) ---
            float m[8];
#pragma unroll
            for (int k = 0; k < 8; ++k) m[k] = 0.f;
            if (deg > 0) {
#pragma unroll
                for (int i = 0; i < 8; ++i) {
                    if (4 * i + g16 < deg) {
#pragma unroll
                        for (int j = 0; j < 4; ++j) {
                            m[2 * j]     += bflo(u4[i][j]);
                            m[2 * j + 1] += bfhi(u4[i][j]);
                        }
                    }
                }
                // combine the 4 subsets (fixed tree across lanes l^16, l^32)
#pragma unroll
                for (int k = 0; k < 8; ++k) m[k] += __shfl_xor(m[k], 16, 64);
#pragma unroll
                for (int k = 0; k < 8; ++k) m[k] += __shfl_xor(m[k], 32, 64);
                // rare tail deg>32 (writer lanes only; after our drain — safe)
                if (deg > 32 && l < 16) {
                    const uint4v* X4 = (const uint4v*)X;
                    for (int i2 = b + 32; i2 < e; ++i2) {
                        int cc = __builtin_amdgcn_readfirstlane(col[i2]);
                        uint4v uu = X4[(long)cc * 16 + q];
#pragma unroll
                        for (int j = 0; j < 4; ++j) {
                            m[2 * j]     += bflo(uu[j]);
                            m[2 * j + 1] += bfhi(uu[j]);
                        }
                    }
                }
                float inv = 1.f / (float)deg;
#pragma unroll
                for (int k = 0; k < 8; ++k) m[k] *= inv;
            }
            // --- 16B swizzled LDS write (lanes 0-15; zeros when deg==0/n>=N) ---
            if (l < 16) {
                uint4v outw;
#pragma unroll
                for (int j = 0; j < 4; ++j)
                    outw[j] = packbf(m[2 * j], m[2 * j + 1]);
                int wi4 = r * 16 + (q ^ (r & 7));
                Msw4[wi4] = outw;
                Ssw4[wi4] = su4;
            }
            b = bn; e = en;
        }
    }
    __syncthreads();
    // ---- MFMA: wave w owns cols [w*16, w*16+16), 2x1 16x16x32 tiles ----
    const int l = t & 63, w = t >> 6;
    const int quad = l >> 4, l15 = l & 15;
    const int wcol = w * 16;
    f32x4 acc[2] = {};
    for (int k0 = 0; k0 < NDIM; k0 += 32) {
        const int kc = k0 + quad * 8;
        short8 ams[2], ass[2], bl, br;
#pragma unroll
        for (int rt = 0; rt < 2; ++rt) {
            int m = rt * 16 + l15;
            ams[rt] = *(const short8*)&Ms[aswz(m, kc)];
            ass[rt] = *(const short8*)&Ss[aswz(m, kc)];
        }
        {
            int n = wcol + l15;
            bl = *(const short8*)&WlT[n * NDIM + kc];
            br = *(const short8*)&WrT[n * NDIM + kc];
        }
#pragma unroll
        for (int rt = 0; rt < 2; ++rt) {
            acc[rt] = __builtin_amdgcn_mfma_f32_16x16x32_bf16(
                ams[rt], bl, acc[rt], 0, 0, 0);
            acc[rt] = __builtin_amdgcn_mfma_f32_16x16x32_bf16(
                ass[rt], br, acc[rt], 0, 0, 0);
        }
    }
    __syncthreads();  // all MFMA LDS reads done; Ms/Ss reusable

    if (OUTMODE == 0) {
        // bf16 out tile row-major in Ms region, then coalesced uint store
        {
            int cg = wcol + l15;
            float bv = biasc[cg];
#pragma unroll
            for (int rt = 0; rt < 2; ++rt)
#pragma unroll
                for (int reg = 0; reg < 4; ++reg) {
                    int row = rt * 16 + quad * 4 + reg;
                    float v = acc[rt][reg] + bv;
                    if (RELU) v = fmaxf(v, 0.f);
                    Ms[row * NDIM + cg] = f2bf(v);
                }
        }
        __syncthreads();
        unsigned* ob = (unsigned*)outp;
        for (int idx = t; idx < MROWS * 64; idx += BTHREADS) {
            int r = idx >> 6;
            if (n0 + r < N) ob[(long)n0 * 64 + idx] = Msw[idx];
        }
    } else {
        // ---- fused: Abf into Ms (aswz) + direct emb store from registers ----
        {
            int cg = wcol + l15;
            float bv = biasc[cg];
#pragma unroll
            for (int rt = 0; rt < 2; ++rt)
#pragma unroll
                for (int reg = 0; reg < 4; ++reg) {
                    int row = rt * 16 + quad * 4 + reg;
                    float v = acc[rt][reg] + bv;
                    Ms[aswz(row, cg)] = f2bf(v);
                    int n = n0 + row;
                    if (n < N) {
                        if (wf) ((float*)outp)[1 + (long)n * NDIM + cg] = v;
                        else ((__hip_bfloat16*)outp)[1 + (long)n * NDIM + cg] =
                                 __float2bfloat16(v);
                    }
                }
        }
        __syncthreads();
        // ---- decoder GEMM from Abf(Ms) ----
        f32x4 acc2[2] = {};
        for (int k0 = 0; k0 < NDIM; k0 += 32) {
            const int kc = k0 + quad * 8;
            short8 a[2], bwd;
#pragma unroll
            for (int rt = 0; rt < 2; ++rt)
                a[rt] = *(const short8*)&Ms[aswz(rt * 16 + l15, kc)];
            bwd = *(const short8*)&WdT[(wcol + l15) * NDIM + kc];
#pragma unroll
            for (int rt = 0; rt < 2; ++rt)
                acc2[rt] = __builtin_amdgcn_mfma_f32_16x16x32_bf16(
                    a[rt], bwd, acc2[rt], 0, 0, 0);
        }
        float lpos = 0.f, lneg = 0.f;
#pragma unroll
        for (int rt = 0; rt < 2; ++rt)
#pragma unroll
            for (int reg = 0; reg < 4; ++reg) {
                int row = rt * 16 + quad * 4 + reg;
                int yn = ylds[row];
                if (yn >= 0) {
                    float z = acc2[rt][reg];
                    float L = log1pf(expf(-fabsf(z)));
                    if (yn) lpos += fmaxf(-z, 0.f) + L;   // softplus(-z)
                    else    lneg += fmaxf(z, 0.f) + L;    // softplus(z)
                }
            }
#pragma unroll
        for (int off = 32; off >= 1; off >>= 1) {
            lpos += __shfl_down(lpos, off, 64);
            lneg += __shfl_down(lneg, off, 64);
        }
        if (l == 0) { redm[w][0] = lpos; redm[w][1] = lneg; }
        __syncthreads();
        if (t == 0) {
            float sp = 0.f, sn = 0.f;
#pragma unroll
            for (int i = 0; i < 8; ++i) { sp += redm[i][0]; sn += redm[i][1]; }
            atomicAdd(&accum[0], sp);
            atomicAdd(&accum[1], sn);
            int c = 0;
            for (int i = 0; i < MROWS; ++i) if (ylds[i] > 0) c++;
            if (c) atomicAdd(npos, c);
        }
    }
}

__global__ void finalize_kernel(const float* __restrict__ accum, const int* __restrict__ npos,
                                const int* __restrict__ flags, void* __restrict__ out, int N) {
    float np_ = (float)(*npos);
    float nn_ = (float)N - np_;
    float l2 = accum[0] / (fmaxf(np_, 1.f) * 128.f);
    float l1 = accum[1] / (fmaxf(nn_, 1.f) * 128.f);
    stf(out, 0, flags[2], l1 + l2);
}

// ---- launch ----------------------------------------------------------------

extern "C" void kernel_launch(void* const* d_in, const int* in_sizes, int n_in,
                              void* d_out, int out_size, void* d_ws, size_t ws_size,
                              hipStream_t stream) {
    const void* x    = d_in[0];
    const int* xedge = (const int*)d_in[1];
    const void* y    = d_in[2];
    const void* W1l  = d_in[4];
    const void* b1l  = d_in[5];
    const void* W1r  = d_in[6];
    const void* W2l  = d_in[7];
    const void* b2l  = d_in[8];
    const void* W2r  = d_in[9];
    const void* Wdec = d_in[10];

    const int N = in_sizes[0] / NDIM;
    const int E = in_sizes[1] / 2;

    char* ws = (char*)d_ws;
    size_t off = 0;
    auto alloc = [&](size_t bytes) -> void* {
        void* p = ws + off;
        off = (off + bytes + 255) & ~(size_t)255;
        return p;
    };
    int*   flags  = (int*)alloc(64);
    // cnt | accum | npos are consecutive: zeroed with ONE memset
    int*   cnt    = (int*)alloc((size_t)N * 4);
    float* accum  = (float*)alloc(64);
    int*   npos   = (int*)alloc(64);
    int*   bsum   = (int*)alloc(1024 * 4);
    int*   rowptr = (int*)alloc((size_t)(N + 1) * 4);
    int*   col    = (int*)alloc((size_t)E * 4);
    unsigned* xb  = (unsigned*)alloc((size_t)N * 64 * 4);
    unsigned* hbuf = (unsigned*)alloc((size_t)N * 64 * 4);
    short* T1l = (short*)alloc(NDIM * NDIM * 2);
    short* T1r = (short*)alloc(NDIM * NDIM * 2);
    short* T2l = (short*)alloc(NDIM * NDIM * 2);
    short* T2r = (short*)alloc(NDIM * NDIM * 2);
    short* Td  = (short*)alloc(NDIM * NDIM * 2);
    float* b1c = (float*)alloc(NDIM * 4);
    float* b2c = (float*)alloc(NDIM * 4);

    const size_t zlen = (((size_t)N * 4 + 255) & ~(size_t)255) + 512;
    hipMemsetAsync(cnt, 0, zlen, stream);   // cnt + accum + npos in one shot

    const long prep_items = (E > NDIM * NDIM) ? E : NDIM * NDIM;
    prep_kernel<<<(int)((prep_items + 255) / 256), 256, 0, stream>>>(
        x, W1l, b1l, W1r, W2l, b2l, W2r, Wdec,
        T1l, T1r, T2l, T2r, Td, b1c, b2c, xb, xedge, E, cnt, N, flags);

    const int sb = (N + SCAN_CHUNK - 1) / SCAN_CHUNK;
    scan_partial<<<sb, 256, 0, stream>>>(cnt, bsum, N, (const unsigned int*)y, flags);
    scan_scatter<<<sb, 256, 0, stream>>>(cnt, bsum, rowptr, N);

    const int eb = (E + 255) / 256;
    fill_kernel<<<eb, 256, 0, stream>>>(xedge, E, flags, cnt, col);

    const int nbM = (N + MROWS - 1) / MROWS;
    // layer 1: reads xb (f32-converted) or x directly (bf16), writes hbuf
    layer_mfma<true, 0><<<nbM, BTHREADS, 0, stream>>>(
        xb, (const unsigned*)x, rowptr, col, T1l, b1c, T1r, nullptr, nullptr,
        flags, hbuf, nullptr, nullptr, N);
    // layer 2 (fused): reads hbuf, writes d_out emb + loss partials
    layer_mfma<false, 1><<<nbM, BTHREADS, 0, stream>>>(
        hbuf, hbuf, rowptr, col, T2l, b2c, T2r, Td, y, flags,
        d_out, accum, npos, N);
    finalize_kernel<<<1, 1, 0, stream>>>(accum, npos, flags, d_out, N);
}

// Round 11
// 305.381 us; speedup vs baseline: 1.0951x; 1.0951x over previous
//
#include <hip/hip_runtime.h>
#include <hip/hip_bf16.h>

#define NDIM 128
#define MROWS 32           // rows per block (two 16-row MFMA tiles)
#define BTHREADS 512       // 8 waves per block
#define SCAN_CHUNK 1024    // per block: 256 threads x 4 elements

typedef __attribute__((ext_vector_type(8))) short short8;
typedef __attribute__((ext_vector_type(4))) float f32x4;

__device__ __forceinline__ float bf2f(__hip_bfloat16 v) { return __bfloat162float(v); }

__device__ __forceinline__ float ldf(const void* p, long i, int f32) {
    return f32 ? ((const float*)p)[i] : bf2f(((const __hip_bfloat16*)p)[i]);
}
__device__ __forceinline__ void stf(void* p, long i, int f32, float v) {
    if (f32) ((float*)p)[i] = v;
    else     ((__hip_bfloat16*)p)[i] = __float2bfloat16(v);
}
__device__ __forceinline__ short f2bf(float v) {
    __hip_bfloat16 h = __float2bfloat16(v);
    short s;
    __builtin_memcpy(&s, &h, 2);
    return s;
}
// bf16x2 packed in a uint: low halfword = even feature, high = odd feature
__device__ __forceinline__ float bflo(unsigned u) { u <<= 16; float f; __builtin_memcpy(&f, &u, 4); return f; }
__device__ __forceinline__ float bfhi(unsigned u) { u &= 0xffff0000u; float f; __builtin_memcpy(&f, &u, 4); return f; }
__device__ __forceinline__ unsigned packbf(float a, float b) {
    unsigned la = (unsigned short)f2bf(a);
    unsigned hb = (unsigned short)f2bf(b);
    return (hb << 16) | la;
}
// Swizzled LDS index (shorts) for A-tiles: 16B-chunk XOR by (row&7).
__device__ __forceinline__ int aswz(int m, int k) {
    return m * NDIM + ((((k >> 3) ^ (m & 7)) << 3) | (k & 7));
}
// Same swizzle at uint (bf16x2) granularity: p = feature-pair index 0..63.
__device__ __forceinline__ int wswz(int m, int p) {
    return m * 64 + ((((p >> 2) ^ (m & 7)) << 2) | (p & 3));
}

// asm-pinned gather load: result VGPR stays allocated and the load cannot be
// sunk into its consumer (R5-R8: every source-level pipeline collapsed;
// VGPR=32 proved it). R9 verified this structure passing at 75us.
#define GLOAD(dst, sa, voff)                                              \
    asm volatile("global_load_dword %0, %1, %2"                           \
                 : "=v"(dst) : "v"(voff), "s"(sa) : "memory")

// ---- prep: per-block dtype detection + weights + biases + degree pass ------

__global__ void prep_kernel(const void* __restrict__ x,
                            const void* __restrict__ W1l, const void* __restrict__ b1l,
                            const void* __restrict__ W1r, const void* __restrict__ W2l,
                            const void* __restrict__ b2l, const void* __restrict__ W2r,
                            const void* __restrict__ Wd,
                            short* __restrict__ T1l, short* __restrict__ T1r,
                            short* __restrict__ T2l, short* __restrict__ T2r,
                            short* __restrict__ Td, float* __restrict__ b1c,
                            float* __restrict__ b2c, unsigned* __restrict__ xb,
                            const int* __restrict__ xedge, int E,
                            int* __restrict__ cnt, int N,
                            int* __restrict__ flags) {
    __shared__ int s_se, s_sc;
    const int t = threadIdx.x;
    if (t == 0) { s_se = 1; s_sc = 0; }
    __syncthreads();
    {
        for (int i = t; i < 512; i += 256)
            if (xedge[2 * i + 1] != 0) s_se = 0;
        const unsigned short* xh = (const unsigned short*)x;
        int c = 0;
        for (int i = t; i < 1024; i += 256) {
            int ex = (xh[2 * i] >> 7) & 0xFF;
            if (ex >= 100 && ex <= 150) c++;
        }
        atomicAdd(&s_sc, c);
    }
    __syncthreads();
    const int e64 = s_se;
    const int wf = (s_sc < 900) ? 1 : 0;
    if (blockIdx.x == 0 && t == 0) {
        flags[0] = e64;
        flags[2] = wf;
    }
    const long idx = (long)blockIdx.x * 256 + t;
    if (idx < E) {
        int d = e64 ? xedge[2 * (E + idx)] : xedge[E + idx];
        atomicAdd(&cnt[d], 1);
    }
    if (idx < NDIM * NDIM) {
        int k = (int)(idx >> 7), n = (int)(idx & 127);
        int o = n * NDIM + k;
        T1l[o] = f2bf(ldf(W1l, idx, wf));
        T1r[o] = f2bf(ldf(W1r, idx, wf));
        T2l[o] = f2bf(ldf(W2l, idx, wf));
        T2r[o] = f2bf(ldf(W2r, idx, wf));
        Td [o] = f2bf(ldf(Wd , idx, wf));
        if (idx < NDIM) { b1c[idx] = ldf(b1l, idx, wf); b2c[idx] = ldf(b2l, idx, wf); }
    }
    if (wf) {
        const long np = (long)N * 64;
        const long stride = (long)gridDim.x * 256;
        for (long pidx = idx; pidx < np; pidx += stride) {
            float2 v = ((const float2*)x)[pidx];
            xb[pidx] = packbf(v.x, v.y);
        }
    }
}

// ---- 2-kernel exclusive scan: partial sums, then scatter with self-prefix --
// (scan_bsums eliminated: each scatter block sums bsum[0..blockIdx) itself —
// <=49 ints, L2-broadcast. y-dtype probe folded into scan_partial block 0.)

__global__ void scan_partial(const int* __restrict__ cnt, int* __restrict__ bsum, int N,
                             const unsigned int* __restrict__ yw,
                             int* __restrict__ flags) {
    __shared__ int red[256];
    const int t = threadIdx.x;
    if (blockIdx.x == 0) {
        __shared__ int s_sy;
        if (t == 0) s_sy = 0;
        __syncthreads();
        for (int i = t; i < 1024; i += 256)
            if (yw[i] > 1u) s_sy = 1;
        __syncthreads();
        if (t == 0) flags[1] = s_sy;
    }
    const long base = (long)blockIdx.x * SCAN_CHUNK + (long)t * 4;
    int s = 0;
#pragma unroll
    for (int i = 0; i < 4; ++i) { long idx = base + i; if (idx < N) s += cnt[idx]; }
    red[t] = s;
    __syncthreads();
    for (int off = 128; off >= 1; off >>= 1) {
        if (t < off) red[t] += red[t + off];
        __syncthreads();
    }
    if (t == 0) bsum[blockIdx.x] = red[0];
}

__global__ void scan_scatter(int* __restrict__ cnt, const int* __restrict__ bsum,
                             int* __restrict__ rowptr, int N) {
    __shared__ int tsum[256];
    __shared__ int red[256];
    const int t = threadIdx.x;
    const long base = (long)blockIdx.x * SCAN_CHUNK + (long)t * 4;
    int loc[4];
    int s = 0;
#pragma unroll
    for (int i = 0; i < 4; ++i) {
        long idx = base + i;
        int c = (idx < N) ? cnt[idx] : 0;
        loc[i] = s;
        s += c;
    }
    tsum[t] = s;
    // self-prefix over previous blocks' sums
    int sown = 0;
    for (int i = t; i < blockIdx.x; i += 256) sown += bsum[i];
    red[t] = sown;
    __syncthreads();
    for (int off = 1; off < 256; off <<= 1) {
        int u = (t >= off) ? tsum[t - off] : 0;
        __syncthreads();
        tsum[t] += u;
        __syncthreads();
    }
    for (int off = 128; off >= 1; off >>= 1) {
        if (t < off) red[t] += red[t + off];
        __syncthreads();
    }
    const int b0 = red[0];
    const int texcl = tsum[t] - s;
#pragma unroll
    for (int i = 0; i < 4; ++i) {
        long idx = base + i;
        if (idx < N) {
            int v = b0 + texcl + loc[i];
            rowptr[idx] = v;
            cnt[idx] = v;   // cursor seed for fill
        }
    }
    if (blockIdx.x == gridDim.x - 1 && t == 255) rowptr[N] = b0 + tsum[255];
}

__global__ void fill_kernel(const int* __restrict__ xedge, int E,
                            const int* __restrict__ flags,
                            int* __restrict__ cur, int* __restrict__ col) {
    int e = blockIdx.x * blockDim.x + threadIdx.x;
    if (e >= E) return;
    const int e64 = flags[0];
    int s = e64 ? xedge[2 * e] : xedge[e];
    int d = e64 ? xedge[2 * (E + e)] : xedge[E + e];
    int p = atomicAdd(&cur[d], 1);
    col[p] = s;
}

// ---- SAGE layer: 32-row blocks, 8 waves, 4 rows/wave. (R9 layer, verified)
// Gather: a row's X-loads (deg-gated groups of 8 + self row) issued as
// inline-asm global_load_dword (SGPR row base + VGPR lane offset), ONE
// s_waitcnt vmcnt(0) per row, pass-through asm on each result, then the
// exact masked-add tree (bit-identical to R4-R9 passing math). Scalar col
// loads (wave-uniform base), clamped. ORDERING (R9 hygiene fix): the rowptr
// prefetch (compiler-tracked load) issues AND is consumed BEFORE the asm
// window, so no compiler vmcnt wait lands inside it.
// OUTMODE 0: bf16 out (outp=hbuf). OUTMODE 1: fused emb store + decoder
// MFMA + BCE loss. Xb = converted bf16x2 (wf==1); Xraw = raw bf16 (wf==0).

template <bool RELU, int OUTMODE>
__global__ __launch_bounds__(BTHREADS, 2)
void layer_mfma(const unsigned* __restrict__ Xb, const unsigned* __restrict__ Xraw,
                const int* __restrict__ rowptr,
                const int* __restrict__ col, const short* __restrict__ WlT,
                const float* __restrict__ biasc, const short* __restrict__ WrT,
                const short* __restrict__ WdT, const void* __restrict__ yv,
                const int* __restrict__ flags, void* __restrict__ outp,
                float* __restrict__ accum, int* __restrict__ npos, int N) {
    __shared__ short AS[2 * MROWS * NDIM];  // [Ms 8KB][Ss 8KB]
    __shared__ int ylds[MROWS];
    __shared__ float redm[8][2];
    short* Ms = AS;
    short* Ss = AS + MROWS * NDIM;
    unsigned* Msw = (unsigned*)Ms;
    unsigned* Ssw = (unsigned*)Ss;
    const int t = threadIdx.x;
    const int n0 = blockIdx.x * MROWS;
    const int wf = flags[2];
    const unsigned* __restrict__ X = wf ? Xb : Xraw;

    if (OUTMODE == 1 && t < MROWS) {
        const int yb = flags[1];
        int n = n0 + t;
        int yn = -1;
        if (n < N)
            yn = yb ? (int)((const unsigned char*)yv)[n]
                    : (((const int*)yv)[n] != 0 ? 1 : 0);
        ylds[t] = yn;
    }

    // ---- gather: 8 row-groups (one wave each), 4 rows/wave ------------------
    {
        const int p = t & 63;
        const unsigned voff = (unsigned)(p * 4);
        const unsigned long long Xb64 = (unsigned long long)(uintptr_t)X;
        const int g = __builtin_amdgcn_readfirstlane(t >> 6);
        int r = g;
        // prologue: first row's rowptr
        int b = 0, e = 0;
        {
            int n = n0 + r;
            if (n < N) {
                b = __builtin_amdgcn_readfirstlane(rowptr[n]);
                e = __builtin_amdgcn_readfirstlane(rowptr[n + 1]);
            }
        }
        for (int it = 0; it < 4; ++it, r += 8) {
            const int n = n0 + r;
            const int deg = e - b;
            // scalar col loads (wave-uniform base), grouped by 8, clamped so
            // garbage beyond deg can't form wild addresses.
            const int* colb = col + b;
            int cs[32];
            if (deg > 0) {
#pragma unroll
                for (int j = 0; j < 8; ++j) {
                    int c = __builtin_amdgcn_readfirstlane(colb[j]);
                    cs[j] = ((unsigned)c >= (unsigned)N) ? 0 : c;
                }
            }
            if (deg > 8) {
#pragma unroll
                for (int j = 8; j < 16; ++j) {
                    int c = __builtin_amdgcn_readfirstlane(colb[j]);
                    cs[j] = ((unsigned)c >= (unsigned)N) ? 0 : c;
                }
            }
            if (deg > 16) {
#pragma unroll
                for (int j = 16; j < 24; ++j) {
                    int c = __builtin_amdgcn_readfirstlane(colb[j]);
                    cs[j] = ((unsigned)c >= (unsigned)N) ? 0 : c;
                }
            }
            if (deg > 24) {
#pragma unroll
                for (int j = 24; j < 32; ++j) {
                    int c = __builtin_amdgcn_readfirstlane(colb[j]);
                    cs[j] = ((unsigned)c >= (unsigned)N) ? 0 : c;
                }
            }
            // rowptr prefetch: compiler-tracked load, consumed NOW (before the
            // asm window) so its implicit wait can't drain our pinned loads.
            int bn = 0, en = 0;
            if (it < 3) {
                int nn = n0 + r + 8;
                if (nn < N) {
                    bn = __builtin_amdgcn_readfirstlane(rowptr[nn]);
                    en = __builtin_amdgcn_readfirstlane(rowptr[nn + 1]);
                }
            }
            // ---- issue ALL loads (asm-pinned; results stay in VGPRs) ----
            unsigned u[32];
            unsigned su = 0;
            if (n < N) {
                unsigned long long sa = Xb64 + ((unsigned long long)(unsigned)n << 8);
                GLOAD(su, sa, voff);
            }
            if (deg > 0) {
#pragma unroll
                for (int j = 0; j < 8; ++j) {
                    unsigned long long sa = Xb64 + ((unsigned long long)(unsigned)cs[j] << 8);
                    GLOAD(u[j], sa, voff);
                }
            }
            if (deg > 8) {
#pragma unroll
                for (int j = 8; j < 16; ++j) {
                    unsigned long long sa = Xb64 + ((unsigned long long)(unsigned)cs[j] << 8);
                    GLOAD(u[j], sa, voff);
                }
            }
            if (deg > 16) {
#pragma unroll
                for (int j = 16; j < 24; ++j) {
                    unsigned long long sa = Xb64 + ((unsigned long long)(unsigned)cs[j] << 8);
                    GLOAD(u[j], sa, voff);
                }
            }
            if (deg > 24) {
#pragma unroll
                for (int j = 24; j < 32; ++j) {
                    unsigned long long sa = Xb64 + ((unsigned long long)(unsigned)cs[j] << 8);
                    GLOAD(u[j], sa, voff);
                }
            }
            // ---- ONE drain for the whole row ----
            asm volatile("s_waitcnt vmcnt(0)" ::: "memory");
            __builtin_amdgcn_sched_barrier(0);
            // pass-through asm: consumption data-depends on post-wait defs
            if (n < N) asm volatile("" : "+v"(su));
            if (deg > 0) {
#pragma unroll
                for (int j = 0; j < 8; ++j) asm volatile("" : "+v"(u[j]));
            }
            if (deg > 8) {
#pragma unroll
                for (int j = 8; j < 16; ++j) asm volatile("" : "+v"(u[j]));
            }
            if (deg > 16) {
#pragma unroll
                for (int j = 16; j < 24; ++j) asm volatile("" : "+v"(u[j]));
            }
            if (deg > 24) {
#pragma unroll
                for (int j = 24; j < 32; ++j) asm volatile("" : "+v"(u[j]));
            }
            // ---- exact masked 8-way partial-sum tree (same order as R4-R9) --
            float m0 = 0.f, m1 = 0.f;
            if (deg > 0) {
                float p0 = 0.f, p1 = 0.f, p2 = 0.f, p3 = 0.f;
                float q0 = 0.f, q1 = 0.f, q2 = 0.f, q3 = 0.f;
#pragma unroll
                for (int j = 0; j < 32; j += 4) {
                    if (j + 0 < deg) { p0 += bflo(u[j]);     q0 += bfhi(u[j]); }
                    if (j + 1 < deg) { p1 += bflo(u[j + 1]); q1 += bfhi(u[j + 1]); }
                    if (j + 2 < deg) { p2 += bflo(u[j + 2]); q2 += bfhi(u[j + 2]); }
                    if (j + 3 < deg) { p3 += bflo(u[j + 3]); q3 += bfhi(u[j + 3]); }
                }
                m0 = (p0 + p1) + (p2 + p3);
                m1 = (q0 + q1) + (q2 + q3);
                for (int i = b + 32; i < e; ++i) {  // rare tail (deg > 32)
                    int c = __builtin_amdgcn_readfirstlane(col[i]);
                    unsigned uu = X[(long)c * 64 + p];
                    m0 += bflo(uu);
                    m1 += bfhi(uu);
                }
                float inv = 1.f / (float)deg;
                m0 *= inv; m1 *= inv;
            }
            int wi = wswz(r, p);
            Msw[wi] = packbf(m0, m1);
            Ssw[wi] = su;
            b = bn; e = en;
        }
    }
    __syncthreads();
    // ---- MFMA: wave w owns cols [w*16, w*16+16), 2x1 16x16x32 tiles ----
    const int l = t & 63, w = t >> 6;
    const int quad = l >> 4, l15 = l & 15;
    const int wcol = w * 16;
    f32x4 acc[2] = {};
    for (int k0 = 0; k0 < NDIM; k0 += 32) {
        const int kc = k0 + quad * 8;
        short8 ams[2], ass[2], bl, br;
#pragma unroll
        for (int rt = 0; rt < 2; ++rt) {
            int m = rt * 16 + l15;
            ams[rt] = *(const short8*)&Ms[aswz(m, kc)];
            ass[rt] = *(const short8*)&Ss[aswz(m, kc)];
        }
        {
            int n = wcol + l15;
            bl = *(const short8*)&WlT[n * NDIM + kc];
            br = *(const short8*)&WrT[n * NDIM + kc];
        }
#pragma unroll
        for (int rt = 0; rt < 2; ++rt) {
            acc[rt] = __builtin_amdgcn_mfma_f32_16x16x32_bf16(
                ams[rt], bl, acc[rt], 0, 0, 0);
            acc[rt] = __builtin_amdgcn_mfma_f32_16x16x32_bf16(
                ass[rt], br, acc[rt], 0, 0, 0);
        }
    }
    __syncthreads();  // all MFMA LDS reads done; Ms/Ss reusable

    if (OUTMODE == 0) {
        // bf16 out tile row-major in Ms region, then coalesced uint store
        {
            int cg = wcol + l15;
            float bv = biasc[cg];
#pragma unroll
            for (int rt = 0; rt < 2; ++rt)
#pragma unroll
                for (int reg = 0; reg < 4; ++reg) {
                    int row = rt * 16 + quad * 4 + reg;
                    float v = acc[rt][reg] + bv;
                    if (RELU) v = fmaxf(v, 0.f);
                    Ms[row * NDIM + cg] = f2bf(v);
                }
        }
        __syncthreads();
        unsigned* ob = (unsigned*)outp;
        for (int idx = t; idx < MROWS * 64; idx += BTHREADS) {
            int r = idx >> 6;
            if (n0 + r < N) ob[(long)n0 * 64 + idx] = Msw[idx];
        }
    } else {
        // ---- fused: Abf into Ms (aswz) + direct emb store from registers ----
        {
            int cg = wcol + l15;
            float bv = biasc[cg];
#pragma unroll
            for (int rt = 0; rt < 2; ++rt)
#pragma unroll
                for (int reg = 0; reg < 4; ++reg) {
                    int row = rt * 16 + quad * 4 + reg;
                    float v = acc[rt][reg] + bv;
                    Ms[aswz(row, cg)] = f2bf(v);
                    int n = n0 + row;
                    if (n < N) {
                        if (wf) ((float*)outp)[1 + (long)n * NDIM + cg] = v;
                        else ((__hip_bfloat16*)outp)[1 + (long)n * NDIM + cg] =
                                 __float2bfloat16(v);
                    }
                }
        }
        __syncthreads();
        // ---- decoder GEMM from Abf(Ms) ----
        f32x4 acc2[2] = {};
        for (int k0 = 0; k0 < NDIM; k0 += 32) {
            const int kc = k0 + quad * 8;
            short8 a[2], bwd;
#pragma unroll
            for (int rt = 0; rt < 2; ++rt)
                a[rt] = *(const short8*)&Ms[aswz(rt * 16 + l15, kc)];
            bwd = *(const short8*)&WdT[(wcol + l15) * NDIM + kc];
#pragma unroll
            for (int rt = 0; rt < 2; ++rt)
                acc2[rt] = __builtin_amdgcn_mfma_f32_16x16x32_bf16(
                    a[rt], bwd, acc2[rt], 0, 0, 0);
        }
        float lpos = 0.f, lneg = 0.f;
#pragma unroll
        for (int rt = 0; rt < 2; ++rt)
#pragma unroll
            for (int reg = 0; reg < 4; ++reg) {
                int row = rt * 16 + quad * 4 + reg;
                int yn = ylds[row];
                if (yn >= 0) {
                    float z = acc2[rt][reg];
                    float L = log1pf(expf(-fabsf(z)));
                    if (yn) lpos += fmaxf(-z, 0.f) + L;   // softplus(-z)
                    else    lneg += fmaxf(z, 0.f) + L;    // softplus(z)
                }
            }
#pragma unroll
        for (int off = 32; off >= 1; off >>= 1) {
            lpos += __shfl_down(lpos, off, 64);
            lneg += __shfl_down(lneg, off, 64);
        }
        if (l == 0) { redm[w][0] = lpos; redm[w][1] = lneg; }
        __syncthreads();
        if (t == 0) {
            float sp = 0.f, sn = 0.f;
#pragma unroll
            for (int i = 0; i < 8; ++i) { sp += redm[i][0]; sn += redm[i][1]; }
            atomicAdd(&accum[0], sp);
            atomicAdd(&accum[1], sn);
            int c = 0;
            for (int i = 0; i < MROWS; ++i) if (ylds[i] > 0) c++;
            if (c) atomicAdd(npos, c);
        }
    }
}

__global__ void finalize_kernel(const float* __restrict__ accum, const int* __restrict__ npos,
                                const int* __restrict__ flags, void* __restrict__ out, int N) {
    float np_ = (float)(*npos);
    float nn_ = (float)N - np_;
    float l2 = accum[0] / (fmaxf(np_, 1.f) * 128.f);
    float l1 = accum[1] / (fmaxf(nn_, 1.f) * 128.f);
    stf(out, 0, flags[2], l1 + l2);
}

// ---- launch ----------------------------------------------------------------

extern "C" void kernel_launch(void* const* d_in, const int* in_sizes, int n_in,
                              void* d_out, int out_size, void* d_ws, size_t ws_size,
                              hipStream_t stream) {
    const void* x    = d_in[0];
    const int* xedge = (const int*)d_in[1];
    const void* y    = d_in[2];
    const void* W1l  = d_in[4];
    const void* b1l  = d_in[5];
    const void* W1r  = d_in[6];
    const void* W2l  = d_in[7];
    const void* b2l  = d_in[8];
    const void* W2r  = d_in[9];
    const void* Wdec = d_in[10];

    const int N = in_sizes[0] / NDIM;
    const int E = in_sizes[1] / 2;

    char* ws = (char*)d_ws;
    size_t off = 0;
    auto alloc = [&](size_t bytes) -> void* {
        void* p = ws + off;
        off = (off + bytes + 255) & ~(size_t)255;
        return p;
    };
    int*   flags  = (int*)alloc(64);
    // cnt | accum | npos are consecutive: zeroed with ONE memset
    int*   cnt    = (int*)alloc((size_t)N * 4);
    float* accum  = (float*)alloc(64);
    int*   npos   = (int*)alloc(64);
    int*   bsum   = (int*)alloc(1024 * 4);
    int*   rowptr = (int*)alloc((size_t)(N + 1) * 4);
    int*   col    = (int*)alloc((size_t)E * 4);
    unsigned* xb  = (unsigned*)alloc((size_t)N * 64 * 4);
    unsigned* hbuf = (unsigned*)alloc((size_t)N * 64 * 4);
    short* T1l = (short*)alloc(NDIM * NDIM * 2);
    short* T1r = (short*)alloc(NDIM * NDIM * 2);
    short* T2l = (short*)alloc(NDIM * NDIM * 2);
    short* T2r = (short*)alloc(NDIM * NDIM * 2);
    short* Td  = (short*)alloc(NDIM * NDIM * 2);
    float* b1c = (float*)alloc(NDIM * 4);
    float* b2c = (float*)alloc(NDIM * 4);

    const size_t zlen = (((size_t)N * 4 + 255) & ~(size_t)255) + 512;
    hipMemsetAsync(cnt, 0, zlen, stream);   // cnt + accum + npos in one shot

    const long prep_items = (E > NDIM * NDIM) ? E : NDIM * NDIM;
    prep_kernel<<<(int)((prep_items + 255) / 256), 256, 0, stream>>>(
        x, W1l, b1l, W1r, W2l, b2l, W2r, Wdec,
        T1l, T1r, T2l, T2r, Td, b1c, b2c, xb, xedge, E, cnt, N, flags);

    const int sb = (N + SCAN_CHUNK - 1) / SCAN_CHUNK;
    scan_partial<<<sb, 256, 0, stream>>>(cnt, bsum, N, (const unsigned int*)y, flags);
    scan_scatter<<<sb, 256, 0, stream>>>(cnt, bsum, rowptr, N);

    const int eb = (E + 255) / 256;
    fill_kernel<<<eb, 256, 0, stream>>>(xedge, E, flags, cnt, col);

    const int nbM = (N + MROWS - 1) / MROWS;
    // layer 1: reads xb (f32-converted) or x directly (bf16), writes hbuf
    layer_mfma<true, 0><<<nbM, BTHREADS, 0, stream>>>(
        xb, (const unsigned*)x, rowptr, col, T1l, b1c, T1r, nullptr, nullptr,
        flags, hbuf, nullptr, nullptr, N);
    // layer 2 (fused): reads hbuf, writes d_out emb + loss partials
    layer_mfma<false, 1><<<nbM, BTHREADS, 0, stream>>>(
        hbuf, hbuf, rowptr, col, T2l, b2c, T2r, Td, y, flags,
        d_out, accum, npos, N);
    finalize_kernel<<<1, 1, 0, stream>>>(accum, npos, flags, d_out, N);
}